// Round 8
// baseline (97.629 us; speedup 1.0000x reference)
//
#include <hip/hip_runtime.h>
#include <stdint.h>

typedef unsigned long long u64;
typedef unsigned int u32;
typedef unsigned short u16;

#define BATCH 64
#define NANCH 8732
#define NCHUNK 1092      // ceil(NANCH/8) u16-chunks (slow path)
#define NCLS 21
#define KCAND 200
#define CAP 2048         // per-(b,c) candidate list capacity
#define PPC 20
#define PTOT 20
#define PRETHR 0.9f

// -------------------- Kernel Z: zero per-(b,c) counters + arrival counters --------------------
__global__ __launch_bounds__(256) void kzero(u32* __restrict__ cnt, u32* __restrict__ arrive)
{
    int i = blockIdx.x * 256 + threadIdx.x;
    if (i < BATCH * NCLS) cnt[i] = 0;
    if (i < BATCH) arrive[i] = 0;
}

// ---------- Kernel A: argmax mask + prefiltered candidate append (vectorized label reads) ----------
__global__ __launch_bounds__(256) void kdecode(
    const float* __restrict__ labels,
    unsigned char* __restrict__ msk, u64* __restrict__ lists,
    u32* __restrict__ cnt, int useT)
{
#pragma clang fp contract(off)
    const int n = blockIdx.x * 256 + threadIdx.x;
    const int b = blockIdx.y;
    const int lane = threadIdx.x & 63;
    const bool active = (n < NANCH);

    float v[NCLS];
#pragma unroll
    for (int c = 0; c < NCLS; ++c) v[c] = 0.0f;
    bool mk = false;
    if (active) {
        const float* lab = labels + ((size_t)b * NANCH + n) * NCLS;
        float4 t[5];
#pragma unroll
        for (int q = 0; q < 5; ++q) __builtin_memcpy(&t[q], lab + q * 4, 16);
#pragma unroll
        for (int q = 0; q < 5; ++q) {
            v[q * 4 + 0] = t[q].x; v[q * 4 + 1] = t[q].y;
            v[q * 4 + 2] = t[q].z; v[q * 4 + 3] = t[q].w;
        }
        v[20] = lab[20];
        float mx = v[0]; int am = 0;
#pragma unroll
        for (int c = 1; c < NCLS; ++c) if (v[c] > mx) { mx = v[c]; am = c; }
        mk = (am != 0);
        msk[(size_t)b * NANCH + n] = mk ? 1 : 0;
    }
    if (!useT) return;

    u32 myHits = 0;
#pragma unroll
    for (int c = 0; c < NCLS; ++c)
        if (active && mk && v[c] >= PRETHR) myHits |= (1u << c);

    u32 myCnt = 0;
#pragma unroll
    for (int c = 0; c < NCLS; ++c) {
        u64 m = __ballot((myHits >> c) & 1u);
        if (lane == c) myCnt = (u32)__popcll(m);
    }
    u32 myBase = 0;
    if (lane < NCLS) myBase = atomicAdd(&cnt[b * NCLS + lane], myCnt);

#pragma unroll
    for (int c = 0; c < NCLS; ++c) {
        u64 m = __ballot((myHits >> c) & 1u);
        u32 base = (u32)__shfl((int)myBase, c, 64);
        if ((m >> lane) & 1ull) {
            u32 rank = (u32)__popcll(m & ((1ull << lane) - 1ull));
            u32 slot = base + rank;
            if (slot < CAP)
                lists[((size_t)b * NCLS + c) * CAP + slot] =
                    ((u64)__float_as_uint(v[c]) << 32) | (u32)(~(u32)n);
        }
    }
}

__device__ __forceinline__ u64 shflxor64(u64 x, int m) {
    return (u64)__shfl_xor((long long)x, m, 64);
}

// Find bin where descending cumulative count crosses `need`; optionally total.
__device__ __forceinline__ void suffixFind(const u32* hist, u32* waveTot, int nb, int need,
                                           int* sSel, int* sAbove, int* sH, int* sTot,
                                           int tid, int lane, int wv)
{
    int K = (nb + 255) >> 8;
    int base = tid * K;
    u32 own = 0;
    for (int q = 0; q < K; ++q) { int bi = base + q; own += (bi < nb) ? hist[bi] : 0u; }
    u32 s = own;
#pragma unroll
    for (int d = 1; d < 64; d <<= 1) {
        u32 o = __shfl_down(s, d, 64);
        if (lane + d < 64) s += o;
    }
    if (lane == 0) waveTot[wv] = s;
    __syncthreads();
    if (tid == 0 && sTot) *sTot = (int)(waveTot[0] + waveTot[1] + waveTot[2] + waveTot[3]);
    u32 add = 0;
    for (int w = wv + 1; w < 4; ++w) add += waveTot[w];
    u32 cum = (s - own) + add;               // strictly above this thread's bins
    for (int q = K - 1; q >= 0; --q) {
        int bi = base + q;
        u32 hh = (bi < nb) ? hist[bi] : 0u;
        if (cum < (u32)need && cum + hh >= (u32)need) { *sSel = bi; *sAbove = (int)cum; *sH = (int)hh; }
        cum += hh;
    }
    __syncthreads();
}

// -------------------- Kernel B: per (b,c) top-200 + NMS + top-20, fused batch merge --------------------
__global__ __launch_bounds__(256) void knms(
    const float* __restrict__ labels, const unsigned char* __restrict__ msk,
    const u64* __restrict__ lists, const u32* __restrict__ cnt,
    const float* __restrict__ deltas, const float* __restrict__ anchors,
    float* __restrict__ clsScores, float* __restrict__ clsBoxes,
    u32* __restrict__ arrive, float* __restrict__ out, int useT)
{
#pragma clang fp contract(off)
    // 8 KB overlay: selection = hist[2048]; post = cb*/cVal/iouT; merge = skey[512]
    __shared__ __align__(16) char smem[8192];
    u32*   hist = (u32*)smem;
    float* cbY1 = (float*)smem;
    float* cbX1 = (float*)(smem + 1024);
    float* cbY2 = (float*)(smem + 2048);
    float* cbX2 = (float*)(smem + 3072);
    float* cbAr = (float*)(smem + 4096);
    float* cVal = (float*)(smem + 5120);
    u64*   iouT = (u64*)(smem + 6144);      // [64][4]
    __shared__ u64 candKey[256];
    __shared__ u32 waveTot[4];
    __shared__ float outS[PPC];
    __shared__ float outB[PPC * 4];
    __shared__ int sSel, sAbove, sH, sTot, sN, sKP, sOld;

    const int tid = threadIdx.x;
    const int lane = tid & 63;
    const int wv = tid >> 6;
    const int bc = blockIdx.x;
    const int b = bc / NCLS;
    const int c = bc % NCLS;

    const int nTHR = useT ? (int)cnt[bc] : -1;
    const bool fast = useT && (nTHR >= KCAND) && (nTHR <= CAP);

    if (fast) {
        // ---- fast path: candidates already prefiltered by kdecode ----
        const u64* lst = lists + (size_t)bc * CAP;
        u64 kr[8];
#pragma unroll
        for (int q = 0; q < 8; ++q) {
            int i = q * 256 + tid;
            kr[q] = (i < nTHR) ? lst[i] : 0ull;
        }
        // hist over bins [1024,2048): t16>>5, all values >= 0.9 > 0.5
        for (int q = tid; q < 1024; q += 256) hist[1024 + q] = 0;
        if (tid == 0) { sSel = -1; sAbove = 0; sH = 0; sN = 0; sKP = 0; }
        __syncthreads();
#pragma unroll
        for (int q = 0; q < 8; ++q) {
            if (q * 256 + tid < nTHR) {
                float v = __uint_as_float((u32)(kr[q] >> 32));
                u32 t = (u32)(v * 65536.0f);
                atomicAdd(&hist[t >> 5], 1u);
            }
        }
        __syncthreads();
        suffixFind(hist + 1024, waveTot, 1024, KCAND, &sSel, &sAbove, &sH, nullptr, tid, lane, wv);
        int A = sAbove;
        u32 T16 = (u32)(1024 + sSel) << 5;
        int cnt2 = A + sH;

        if (cnt2 > 256) {   // exact-t16 refinement (practically never)
            if (tid < 32) hist[tid] = 0;
            if (tid == 0) { sSel = -1; sAbove = 0; sH = 0; }
            __syncthreads();
#pragma unroll
            for (int q = 0; q < 8; ++q) {
                if (q * 256 + tid < nTHR) {
                    float v = __uint_as_float((u32)(kr[q] >> 32));
                    u32 t = (u32)(v * 65536.0f);
                    if (t >= T16 && t < T16 + 32) atomicAdd(&hist[t - T16], 1u);
                }
            }
            __syncthreads();
            suffixFind(hist, waveTot, 32, KCAND - A, &sSel, &sAbove, &sH, nullptr, tid, lane, wv);
            A += sAbove;
            T16 += (u32)sSel;
        }
        // compact t16 >= T16 (superset of exact top-200 incl. all ties)
#pragma unroll
        for (int q = 0; q < 8; ++q) {
            if (q * 256 + tid < nTHR) {
                float v = __uint_as_float((u32)(kr[q] >> 32));
                u32 t = (u32)(v * 65536.0f);
                if (t >= T16) {
                    int slot = atomicAdd(&sN, 1);
                    if (slot < 256) candKey[slot] = kr[q];
                }
            }
        }
    } else {
        // ---- slow fallback: full scan from labels+msk (rarely taken) ----
        uint4 rc[5];
        for (int q = 0; q < 5; ++q) {
            int chunk = q * 256 + tid;
            u32 w4[4] = {0, 0, 0, 0};
            if (chunk < NCHUNK) {
                for (int w = 0; w < 4; ++w)
                    for (int h = 0; h < 2; ++h) {
                        int n = chunk * 8 + w * 2 + h;
                        u32 t = 0;
                        if (n < NANCH && msk[(size_t)b * NANCH + n]) {
                            float v = labels[((size_t)b * NANCH + n) * NCLS + c];
                            t = (u32)(v * 65536.0f);
                        }
                        w4[w] |= t << (16 * h);
                    }
            }
            rc[q] = make_uint4(w4[0], w4[1], w4[2], w4[3]);
        }
        for (int q = tid; q < 1024; q += 256) hist[1024 + q] = 0;
        if (tid == 0) { sSel = -1; sAbove = 0; sH = 0; sTot = 0; sN = 0; sKP = 0; }
        __syncthreads();
#pragma unroll
        for (int q = 0; q < 5; ++q) {
            if (q * 256 + tid < NCHUNK) {
                u32 w4[4] = {rc[q].x, rc[q].y, rc[q].z, rc[q].w};
#pragma unroll
                for (int w = 0; w < 4; ++w) {
                    u32 lo = w4[w] & 0xFFFFu, hi = w4[w] >> 16;
                    if (lo & 0x8000u) atomicAdd(&hist[lo >> 5], 1u);
                    if (hi & 0x8000u) atomicAdd(&hist[hi >> 5], 1u);
                }
            }
        }
        __syncthreads();
        suffixFind(hist + 1024, waveTot, 1024, KCAND, &sSel, &sAbove, &sH, &sTot, tid, lane, wv);
        int A; int cnt2; u32 T16;
        if (sTot < KCAND) { T16 = 32768u; A = 0; cnt2 = sTot; }
        else { A = sAbove; T16 = (u32)(1024 + sSel) << 5; cnt2 = A + sH; }
        if (cnt2 > 256) {
            if (tid < 32) hist[tid] = 0;
            if (tid == 0) { sSel = -1; sAbove = 0; sH = 0; }
            __syncthreads();
#pragma unroll
            for (int q = 0; q < 5; ++q) {
                if (q * 256 + tid < NCHUNK) {
                    u32 w4[4] = {rc[q].x, rc[q].y, rc[q].z, rc[q].w};
#pragma unroll
                    for (int w = 0; w < 4; ++w) {
                        u32 lo = w4[w] & 0xFFFFu, hi = w4[w] >> 16;
                        if (lo >= T16 && lo < T16 + 32) atomicAdd(&hist[lo - T16], 1u);
                        if (hi >= T16 && hi < T16 + 32) atomicAdd(&hist[hi - T16], 1u);
                    }
                }
            }
            __syncthreads();
            suffixFind(hist, waveTot, 32, KCAND - A, &sSel, &sAbove, &sH, nullptr, tid, lane, wv);
            A += sAbove;
            T16 += (u32)sSel;
        }
#pragma unroll
        for (int q = 0; q < 5; ++q) {
            int chunk = q * 256 + tid;
            if (chunk < NCHUNK) {
                u32 w4[4] = {rc[q].x, rc[q].y, rc[q].z, rc[q].w};
#pragma unroll
                for (int w = 0; w < 4; ++w) {
#pragma unroll
                    for (int h = 0; h < 2; ++h) {
                        u32 t = (h == 0) ? (w4[w] & 0xFFFFu) : (w4[w] >> 16);
                        if (t >= T16) {
                            int n = chunk * 8 + w * 2 + h;
                            float v = labels[((size_t)b * NANCH + n) * NCLS + c];
                            int slot = atomicAdd(&sN, 1);
                            if (slot < 256)
                                candKey[slot] = ((u64)__float_as_uint(v) << 32) | (u32)(~(u32)n);
                        }
                    }
                }
            }
        }
    }
    __syncthreads();
    int nc = sN; if (nc > 256) nc = 256;

    // ---- register bitonic sort desc on 256 keys (shfl_xor j<64, LDS j>=64) ----
    u64 x = (tid < nc) ? candKey[tid] : 0ull;
    for (int k = 2; k <= 256; k <<= 1) {
        for (int j = k >> 1; j > 0; j >>= 1) {
            u64 y;
            if (j < 64) {
                y = shflxor64(x, j);
            } else {
                __syncthreads();
                candKey[tid] = x;
                __syncthreads();
                y = candKey[tid ^ j];
            }
            bool keepMax = ((tid & k) == 0) == ((tid & j) == 0);
            u64 mx = (x > y) ? x : y;
            u64 mn = (x > y) ? y : x;
            x = keepMax ? mx : mn;
        }
    }
    // x = tid-th largest (value desc, index asc) == exact top_k order

    // ---- on-demand box decode for own candidate ----
    float myV = __uint_as_float((u32)(x >> 32));
    float myY1 = 0.f, myX1 = 0.f, myY2 = 0.f, myX2 = 0.f, myAr = 0.f;
    u32 idx = ~(u32)x;
    if (tid < KCAND && idx < (u32)NANCH) {
        float4 d = ((const float4*)deltas)[(size_t)b * NANCH + idx];
        float4 a = ((const float4*)anchors)[idx];
        float ah = a.z - a.x, aw = a.w - a.y;
        float acy = a.x + 0.5f * ah, acx = a.y + 0.5f * aw;
        float cy = (d.x * 0.1f) * ah + acy;
        float cx = (d.y * 0.1f) * aw + acx;
        float hh2 = expf(d.z * 0.2f) * ah;
        float ww2 = expf(d.w * 0.2f) * aw;
        myY1 = cy - 0.5f * hh2; myX1 = cx - 0.5f * ww2;
        myY2 = cy + 0.5f * hh2; myX2 = cx + 0.5f * ww2;
        myAr = (myY2 - myY1) * (myX2 - myX1);
    } else {
        myV = 0.f;
    }
    __syncthreads();   // selection-phase LDS reads done before overlay write
    cbY1[tid] = myY1; cbX1[tid] = myX1; cbY2[tid] = myY2; cbX2[tid] = myX2;
    cbAr[tid] = myAr; cVal[tid] = myV;

    // ---- tiled IoU + serial NMS with early exit at 20 kept ----
    u64 k0 = 0, k1 = 0, k2 = 0, k3 = 0;
    int KPw = 0;
    for (int t0 = 0; t0 < 4; ++t0) {
        __syncthreads();                  // cb/iouT ready or free; sKP visible
        if (sKP >= PPC) break;            // uniform across block
        int rowBase = t0 * 64;
        int rows = KCAND - rowBase; if (rows > 64) rows = 64;
        for (int r = wv; r < rows; r += 4) {
            int i = rowBase + r;
            float y1i = cbY1[i], x1i = cbX1[i], y2i = cbY2[i], x2i = cbX2[i], ari = cbAr[i];
            for (int cg = 0; cg <= t0; ++cg) {
                int j = cg * 64 + lane;
                float ih = fminf(y2i, cbY2[j]) - fmaxf(y1i, cbY1[j]);
                ih = fmaxf(ih, 0.0f);
                float iw = fminf(x2i, cbX2[j]) - fmaxf(x1i, cbX1[j]);
                iw = fmaxf(iw, 0.0f);
                float inter = ih * iw;
                float iou = inter / (ari + cbAr[j] - inter + 1e-8f);
                u64 bal = __ballot(iou > 0.5f);
                if (lane == 0) iouT[r * 4 + cg] = bal;
            }
        }
        __syncthreads();                  // iouT ready
        if (tid < 64) {
            int i = rowBase + lane;
            u64 r0 = 0, r1 = 0, r2 = 0, r3 = 0;
            bool vld = false;
            if (lane < rows) {
                r0 = iouT[lane * 4 + 0]; r1 = iouT[lane * 4 + 1];
                r2 = iouT[lane * 4 + 2]; r3 = iouT[lane * 4 + 3];
                vld = cVal[i] > 0.5f;
            }
            for (int l = 0; l < rows; ++l) {
                int mydec = (vld && !((k0 & r0) | (k1 & r1) | (k2 & r2) | (k3 & r3))) ? 1 : 0;
                int d = __shfl(mydec, l, 64);
                if (d) {
                    u64 bit = 1ull << l;
                    if (t0 == 0) k0 |= bit; else if (t0 == 1) k1 |= bit;
                    else if (t0 == 2) k2 |= bit; else k3 |= bit;
                    ++KPw;
                    if (KPw >= PPC) break;   // uniform within wave (d broadcast)
                }
            }
            if (tid == 0) sKP = KPw;
        }
    }
    __syncthreads();

    if (tid < PPC) outS[tid] = 0.0f;
    if (tid < PPC * 4) outB[tid] = 0.0f;
    __syncthreads();

    // ---- emit first 20 kept (== top_k(kept_scores, 20) since values sorted) ----
    if (tid < 64) {
        int base = 0;
#pragma unroll
        for (int chunk = 0; chunk < 4; ++chunk) {
            u64 kw = (chunk == 0) ? k0 : (chunk == 1) ? k1 : (chunk == 2) ? k2 : k3;
            int i = chunk * 64 + tid;
            bool kept = ((kw >> tid) & 1ull) != 0;
            int rank = base + (int)__popcll(kw & ((1ull << tid) - 1ull));
            if (kept && rank < PPC && i < KCAND) {
                outS[rank] = cVal[i];
                outB[rank * 4 + 0] = cbY1[i];
                outB[rank * 4 + 1] = cbX1[i];
                outB[rank * 4 + 2] = cbY2[i];
                outB[rank * 4 + 3] = cbX2[i];
            }
            base += (int)__popcll(kw);
        }
    }
    __syncthreads();
    if (tid < PPC) clsScores[(size_t)bc * PPC + tid] = outS[tid];
    if (tid < PPC * 4) clsBoxes[(size_t)bc * PPC * 4 + tid] = outB[tid];

    if (!useT) return;   // standalone kmerge handles the merge

    // ---- fused per-batch merge: last-arriving block of batch b merges ----
    __syncthreads();                      // drains vmcnt: publishes stores to L2
    if (tid == 0) {
        __threadfence();                  // L2 writeback to device scope
        sOld = (int)atomicAdd(&arrive[b], 1u);
    }
    __syncthreads();
    if (sOld != NCLS - 1) return;
    __threadfence();                      // acquire side

    const int F = NCLS * PPC;             // 420
    u64* skey = (u64*)smem;               // overlay (cb*/iouT dead now)
    u64 x0, x1;
    {
        float v0 = __hip_atomic_load(&clsScores[(size_t)b * F + tid],
                                     __ATOMIC_RELAXED, __HIP_MEMORY_SCOPE_AGENT);
        x0 = ((u64)__float_as_uint(v0) << 32) | (u32)(~(u32)tid);
        int i1 = tid + 256;
        if (i1 < F) {
            float v1 = __hip_atomic_load(&clsScores[(size_t)b * F + i1],
                                         __ATOMIC_RELAXED, __HIP_MEMORY_SCOPE_AGENT);
            x1 = ((u64)__float_as_uint(v1) << 32) | (u32)(~(u32)i1);
        } else x1 = 0ull;
    }
    for (int k = 2; k <= 512; k <<= 1) {
        for (int j = k >> 1; j >= 1; j >>= 1) {
            if (j >= 256) {               // intra-thread pair (v, v^256)
                bool km = ((tid & k) == 0) == (((tid) & j & 255) == 0);  // v0&j==0 for j=256
                // j==256, v0=tid<256 -> v0&j==0 -> km = ((tid&k)==0); k=512 -> always true
                u64 mx = x0 > x1 ? x0 : x1, mn = x0 > x1 ? x1 : x0;
                x0 = km ? mx : mn; x1 = km ? mn : mx;
            } else if (j >= 64) {         // LDS exchange
                __syncthreads();
                skey[tid] = x0; skey[tid + 256] = x1;
                __syncthreads();
                u64 y0 = skey[tid ^ j], y1 = skey[(tid ^ j) + 256];
                {
                    bool km = ((tid & k) == 0) == ((tid & j) == 0);
                    u64 mx = x0 > y0 ? x0 : y0, mn = x0 > y0 ? y0 : x0;
                    x0 = km ? mx : mn;
                }
                {
                    int v1i = tid + 256;
                    bool km = ((v1i & k) == 0) == ((tid & j) == 0);
                    u64 mx = x1 > y1 ? x1 : y1, mn = x1 > y1 ? y1 : x1;
                    x1 = km ? mx : mn;
                }
            } else {                      // shfl exchange
                u64 y0 = shflxor64(x0, j), y1 = shflxor64(x1, j);
                {
                    bool km = ((tid & k) == 0) == ((tid & j) == 0);
                    u64 mx = x0 > y0 ? x0 : y0, mn = x0 > y0 ? y0 : x0;
                    x0 = km ? mx : mn;
                }
                {
                    int v1i = tid + 256;
                    bool km = ((v1i & k) == 0) == ((tid & j) == 0);
                    u64 mx = x1 > y1 ? x1 : y1, mn = x1 > y1 ? y1 : x1;
                    x1 = km ? mx : mn;
                }
            }
        }
    }
    if (tid < PTOT) {
        float v = __uint_as_float((u32)(x0 >> 32));
        u32 f = ~((u32)x0);
        bool valid = (v > 0.0f) && (f < (u32)F);
        float cls = valid ? (float)(f / PPC) : 0.0f;
        float* oB = out;
        float* oV = out + (size_t)BATCH * PTOT * 4;
        float* oL = oV + (size_t)BATCH * PTOT;
#pragma unroll
        for (int q = 0; q < 4; ++q) {
            float xq = 0.0f;
            if (valid) {
                xq = __hip_atomic_load(&clsBoxes[((size_t)b * F + f) * 4 + q],
                                       __ATOMIC_RELAXED, __HIP_MEMORY_SCOPE_AGENT);
                xq = fminf(fmaxf(xq, 0.0f), 1.0f);
            }
            oB[((size_t)b * PTOT + tid) * 4 + q] = xq;
        }
        oV[(size_t)b * PTOT + tid] = v;
        oL[(size_t)b * PTOT + tid] = cls;
    }
}

// -------------------- Kernel C: standalone merge (only for !useT fallback) --------------------
__global__ __launch_bounds__(512) void kmerge(
    const float* __restrict__ clsScores, const float* __restrict__ clsBoxes,
    float* __restrict__ out)
{
#pragma clang fp contract(off)
    __shared__ u64 key[512];
    const int tid = threadIdx.x;
    const int b = blockIdx.x;
    const int F = NCLS * PPC;  // 420
    u64 kk = 0;
    if (tid < F) {
        float v = clsScores[(size_t)b * F + tid];
        kk = ((u64)__float_as_uint(v) << 32) | (u32)(~(u32)tid);
    }
    key[tid] = kk;
    for (int k = 2; k <= 512; k <<= 1)
        for (int j = k >> 1; j > 0; j >>= 1) {
            __syncthreads();
            int ixj = tid ^ j;
            if (ixj > tid) {
                u64 a = key[tid], bb = key[ixj];
                if (((tid & k) == 0) ? (a < bb) : (a > bb)) { key[tid] = bb; key[ixj] = a; }
            }
        }
    __syncthreads();
    if (tid < PTOT) {
        u64 kx = key[tid];
        float v = __uint_as_float((u32)(kx >> 32));
        u32 f = ~((u32)kx);
        bool valid = (v > 0.0f) && (f < (u32)F);
        float cls = valid ? (float)(f / PPC) : 0.0f;
        float* oB = out;
        float* oV = out + (size_t)BATCH * PTOT * 4;
        float* oL = oV + (size_t)BATCH * PTOT;
#pragma unroll
        for (int q = 0; q < 4; ++q) {
            float xq = 0.0f;
            if (valid) {
                xq = clsBoxes[((size_t)b * F + f) * 4 + q];
                xq = fminf(fmaxf(xq, 0.0f), 1.0f);
            }
            oB[((size_t)b * PTOT + tid) * 4 + q] = xq;
        }
        oV[(size_t)b * PTOT + tid] = v;
        oL[(size_t)b * PTOT + tid] = cls;
    }
}

extern "C" void kernel_launch(void* const* d_in, const int* in_sizes, int n_in,
                              void* d_out, int out_size, void* d_ws, size_t ws_size,
                              hipStream_t stream)
{
    const float* deltas  = (const float*)d_in[0];
    const float* labels  = (const float*)d_in[1];
    const float* anchors = (const float*)d_in[2];
    float* out = (float*)d_out;
    char* ws = (char*)d_ws;

    // ws layout (256B aligned)
    const size_t mskOff  = 0;          // B*N u8            =    558,848
    const size_t cntOff  = 558848;     // B*C u32           =      5,376
    const size_t arrOff  = 564224;     // B u32             =        256
    const size_t csOff   = 564480;     // B*C*20 f32        =    107,520
    const size_t cbOff   = 672000;     // B*C*20*4 f32      =    430,080
    const size_t listOff = 1102336;    // B*C*CAP u64       = 22,020,096
    const size_t needT   = 23122432;

    unsigned char* msk = (unsigned char*)(ws + mskOff);
    u32* cnt         = (u32*)(ws + cntOff);
    u32* arrive      = (u32*)(ws + arrOff);
    float* clsScores = (float*)(ws + csOff);
    float* clsBoxes  = (float*)(ws + cbOff);
    u64* lists       = (u64*)(ws + listOff);
    int useT = (ws_size >= needT) ? 1 : 0;

    if (useT) kzero<<<(BATCH * NCLS + 255) / 256, 256, 0, stream>>>(cnt, arrive);
    dim3 gA((NANCH + 255) / 256, BATCH);
    kdecode<<<gA, 256, 0, stream>>>(labels, msk, lists, cnt, useT);
    knms<<<BATCH * NCLS, 256, 0, stream>>>(labels, msk, lists, cnt, deltas, anchors,
                                           clsScores, clsBoxes, arrive, out, useT);
    if (!useT) kmerge<<<BATCH, 512, 0, stream>>>(clsScores, clsBoxes, out);
}

// Round 9
// 84.564 us; speedup vs baseline: 1.1545x; 1.1545x over previous
//
#include <hip/hip_runtime.h>
#include <stdint.h>

typedef unsigned long long u64;
typedef unsigned int u32;
typedef unsigned short u16;

#define BATCH 64
#define NANCH 8732
#define NCHUNK 1092      // ceil(NANCH/8) u16-chunks (slow path)
#define NCLS 21
#define KCAND 200
#define CAP 2048         // per-(b,c) candidate list capacity
#define SORTN 1024       // fast-path direct-sort width
#define PPC 20
#define PTOT 20
#define PRETHR 0.9f

// ---------- Kernel A: argmax mask + prefiltered candidate append ----------
__global__ __launch_bounds__(256) void kdecode(
    const float* __restrict__ labels,
    unsigned char* __restrict__ msk, u64* __restrict__ lists,
    u32* __restrict__ cnt, int useT)
{
#pragma clang fp contract(off)
    const int n = blockIdx.x * 256 + threadIdx.x;
    const int b = blockIdx.y;
    const int lane = threadIdx.x & 63;
    const bool active = (n < NANCH);

    float v[NCLS];
#pragma unroll
    for (int c = 0; c < NCLS; ++c) v[c] = 0.0f;
    bool mk = false;
    if (active) {
        const float* lab = labels + ((size_t)b * NANCH + n) * NCLS;
#pragma unroll
        for (int c = 0; c < NCLS; ++c) v[c] = lab[c];
        float mx = v[0]; int am = 0;
#pragma unroll
        for (int c = 1; c < NCLS; ++c) if (v[c] > mx) { mx = v[c]; am = c; }
        mk = (am != 0);
        msk[(size_t)b * NANCH + n] = mk ? 1 : 0;
    }
    if (!useT) return;

    u32 myHits = 0;
#pragma unroll
    for (int c = 0; c < NCLS; ++c)
        if (active && mk && v[c] >= PRETHR) myHits |= (1u << c);

    u32 myCnt = 0;
#pragma unroll
    for (int c = 0; c < NCLS; ++c) {
        u64 m = __ballot((myHits >> c) & 1u);
        if (lane == c) myCnt = (u32)__popcll(m);
    }
    u32 myBase = 0;
    if (lane < NCLS) myBase = atomicAdd(&cnt[b * NCLS + lane], myCnt);

#pragma unroll
    for (int c = 0; c < NCLS; ++c) {
        u64 m = __ballot((myHits >> c) & 1u);
        u32 base = (u32)__shfl((int)myBase, c, 64);
        if ((m >> lane) & 1ull) {
            u32 rank = (u32)__popcll(m & ((1ull << lane) - 1ull));
            u32 slot = base + rank;
            if (slot < CAP)
                lists[((size_t)b * NCLS + c) * CAP + slot] =
                    ((u64)__float_as_uint(v[c]) << 32) | (u32)(~(u32)n);
        }
    }
}

__device__ __forceinline__ u64 shflxor64(u64 x, int m) {
    return (u64)__shfl_xor((long long)x, m, 64);
}

#define CMPXP(a, b, km) { u64 mx_ = (a) > (b) ? (a) : (b); u64 mn_ = (a) > (b) ? (b) : (a); \
                          (a) = (km) ? mx_ : mn_; (b) = (km) ? mn_ : mx_; }

// Find bin where descending cumulative count crosses `need`; optionally total. (slow path)
__device__ __forceinline__ void suffixFind(const u32* hist, u32* waveTot, int nb, int need,
                                           int* sSel, int* sAbove, int* sH, int* sTot,
                                           int tid, int lane, int wv)
{
    int K = (nb + 255) >> 8;
    int base = tid * K;
    u32 own = 0;
    for (int q = 0; q < K; ++q) { int bi = base + q; own += (bi < nb) ? hist[bi] : 0u; }
    u32 s = own;
#pragma unroll
    for (int d = 1; d < 64; d <<= 1) {
        u32 o = __shfl_down(s, d, 64);
        if (lane + d < 64) s += o;
    }
    if (lane == 0) waveTot[wv] = s;
    __syncthreads();
    if (tid == 0 && sTot) *sTot = (int)(waveTot[0] + waveTot[1] + waveTot[2] + waveTot[3]);
    u32 add = 0;
    for (int w = wv + 1; w < 4; ++w) add += waveTot[w];
    u32 cum = (s - own) + add;               // strictly above this thread's bins
    for (int q = K - 1; q >= 0; --q) {
        int bi = base + q;
        u32 hh = (bi < nb) ? hist[bi] : 0u;
        if (cum < (u32)need && cum + hh >= (u32)need) { *sSel = bi; *sAbove = (int)cum; *sH = (int)hh; }
        cum += hh;
    }
    __syncthreads();
}

// -------------------- Kernel B: per (b,c) top-200 + NMS + top-20 --------------------
__global__ __launch_bounds__(256) void knms(
    const float* __restrict__ labels, const unsigned char* __restrict__ msk,
    const u64* __restrict__ lists, const u32* __restrict__ cnt,
    const float* __restrict__ deltas, const float* __restrict__ anchors,
    float* __restrict__ clsScores, float* __restrict__ clsBoxes, int useT)
{
#pragma clang fp contract(off)
    // 8 KB overlay: fast sort buf / slow hist[2048]; post = cb*/cVal/iouT
    __shared__ __align__(16) char smem[8192];
    u64*   sbuf = (u64*)smem;               // [1024] fast-path exchange buffer
    u32*   hist = (u32*)smem;               // slow path
    float* cbY1 = (float*)smem;
    float* cbX1 = (float*)(smem + 1024);
    float* cbY2 = (float*)(smem + 2048);
    float* cbX2 = (float*)(smem + 3072);
    float* cbAr = (float*)(smem + 4096);
    float* cVal = (float*)(smem + 5120);
    u64*   iouT = (u64*)(smem + 6144);      // [64][4]
    __shared__ u64 candKey[256];
    __shared__ u32 waveTot[4];
    __shared__ float outS[PPC];
    __shared__ float outB[PPC * 4];
    __shared__ int sSel, sAbove, sH, sTot, sN, sKP;

    const int tid = threadIdx.x;
    const int lane = tid & 63;
    const int wv = tid >> 6;
    const int bc = blockIdx.x;
    const int b = bc / NCLS;
    const int c = bc % NCLS;

    const int nTHR = useT ? (int)cnt[bc] : -1;
    const bool fast = useT && (nTHR >= KCAND) && (nTHR <= SORTN);

    u64 x;   // converged: tid-th largest key (value desc, index asc) == top_k order
    if (fast) {
        // ---- fast path: direct 1024-key register bitonic sort (4 keys/lane) ----
        if (tid == 0) sKP = 0;
        const u64* lst = lists + (size_t)bc * CAP;
        u64 xr[4];
#pragma unroll
        for (int s = 0; s < 4; ++s) {
            int i = s * 256 + tid;
            xr[s] = (i < nTHR) ? lst[i] : 0ull;
        }
        for (int k = 2; k <= SORTN; k <<= 1) {
            for (int j = k >> 1; j >= 1; j >>= 1) {
                if (j == 512) {
                    CMPXP(xr[0], xr[2], true); CMPXP(xr[1], xr[3], true);
                } else if (j == 256) {
                    bool km23 = (k == 1024);
                    CMPXP(xr[0], xr[1], true); CMPXP(xr[2], xr[3], km23);
                } else if (j >= 64) {
                    __syncthreads();
#pragma unroll
                    for (int s = 0; s < 4; ++s) sbuf[s * 256 + tid] = xr[s];
                    __syncthreads();
#pragma unroll
                    for (int s = 0; s < 4; ++s) {
                        u64 y = sbuf[s * 256 + (tid ^ j)];
                        bool km = (((s * 256 + tid) & k) == 0) == ((tid & j) == 0);
                        u64 mx = xr[s] > y ? xr[s] : y;
                        u64 mn = xr[s] > y ? y : xr[s];
                        xr[s] = km ? mx : mn;
                    }
                } else {
#pragma unroll
                    for (int s = 0; s < 4; ++s) {
                        u64 y = shflxor64(xr[s], j);
                        bool km = (((s * 256 + tid) & k) == 0) == ((tid & j) == 0);
                        u64 mx = xr[s] > y ? xr[s] : y;
                        u64 mn = xr[s] > y ? y : xr[s];
                        xr[s] = km ? mx : mn;
                    }
                }
            }
        }
        x = xr[0];   // positions 0..255 live in slot 0; position == tid
    } else {
        // ---- slow fallback: full scan from labels+msk (rarely taken; R5-verbatim) ----
        uint4 rc[5];
        for (int q = 0; q < 5; ++q) {
            int chunk = q * 256 + tid;
            u32 w4[4] = {0, 0, 0, 0};
            if (chunk < NCHUNK) {
                for (int w = 0; w < 4; ++w)
                    for (int h = 0; h < 2; ++h) {
                        int n = chunk * 8 + w * 2 + h;
                        u32 t = 0;
                        if (n < NANCH && msk[(size_t)b * NANCH + n]) {
                            float v = labels[((size_t)b * NANCH + n) * NCLS + c];
                            t = (u32)(v * 65536.0f);
                        }
                        w4[w] |= t << (16 * h);
                    }
            }
            rc[q] = make_uint4(w4[0], w4[1], w4[2], w4[3]);
        }
        for (int q = tid; q < 1024; q += 256) hist[1024 + q] = 0;
        if (tid == 0) { sSel = -1; sAbove = 0; sH = 0; sTot = 0; sN = 0; sKP = 0; }
        __syncthreads();
#pragma unroll
        for (int q = 0; q < 5; ++q) {
            if (q * 256 + tid < NCHUNK) {
                u32 w4[4] = {rc[q].x, rc[q].y, rc[q].z, rc[q].w};
#pragma unroll
                for (int w = 0; w < 4; ++w) {
                    u32 lo = w4[w] & 0xFFFFu, hi = w4[w] >> 16;
                    if (lo & 0x8000u) atomicAdd(&hist[lo >> 5], 1u);
                    if (hi & 0x8000u) atomicAdd(&hist[hi >> 5], 1u);
                }
            }
        }
        __syncthreads();
        suffixFind(hist + 1024, waveTot, 1024, KCAND, &sSel, &sAbove, &sH, &sTot, tid, lane, wv);
        int A; int cnt2; u32 T16;
        if (sTot < KCAND) { T16 = 32768u; A = 0; cnt2 = sTot; }
        else { A = sAbove; T16 = (u32)(1024 + sSel) << 5; cnt2 = A + sH; }
        if (cnt2 > 256) {
            if (tid < 32) hist[tid] = 0;
            if (tid == 0) { sSel = -1; sAbove = 0; sH = 0; }
            __syncthreads();
#pragma unroll
            for (int q = 0; q < 5; ++q) {
                if (q * 256 + tid < NCHUNK) {
                    u32 w4[4] = {rc[q].x, rc[q].y, rc[q].z, rc[q].w};
#pragma unroll
                    for (int w = 0; w < 4; ++w) {
                        u32 lo = w4[w] & 0xFFFFu, hi = w4[w] >> 16;
                        if (lo >= T16 && lo < T16 + 32) atomicAdd(&hist[lo - T16], 1u);
                        if (hi >= T16 && hi < T16 + 32) atomicAdd(&hist[hi - T16], 1u);
                    }
                }
            }
            __syncthreads();
            suffixFind(hist, waveTot, 32, KCAND - A, &sSel, &sAbove, &sH, nullptr, tid, lane, wv);
            A += sAbove;
            T16 += (u32)sSel;
        }
#pragma unroll
        for (int q = 0; q < 5; ++q) {
            int chunk = q * 256 + tid;
            if (chunk < NCHUNK) {
                u32 w4[4] = {rc[q].x, rc[q].y, rc[q].z, rc[q].w};
#pragma unroll
                for (int w = 0; w < 4; ++w) {
#pragma unroll
                    for (int h = 0; h < 2; ++h) {
                        u32 t = (h == 0) ? (w4[w] & 0xFFFFu) : (w4[w] >> 16);
                        if (t >= T16) {
                            int n = chunk * 8 + w * 2 + h;
                            float v = labels[((size_t)b * NANCH + n) * NCLS + c];
                            int slot = atomicAdd(&sN, 1);
                            if (slot < 256)
                                candKey[slot] = ((u64)__float_as_uint(v) << 32) | (u32)(~(u32)n);
                        }
                    }
                }
            }
        }
        __syncthreads();
        int nc = sN; if (nc > 256) nc = 256;
        x = (tid < nc) ? candKey[tid] : 0ull;
        for (int k = 2; k <= 256; k <<= 1) {
            for (int j = k >> 1; j > 0; j >>= 1) {
                u64 y;
                if (j < 64) {
                    y = shflxor64(x, j);
                } else {
                    __syncthreads();
                    candKey[tid] = x;
                    __syncthreads();
                    y = candKey[tid ^ j];
                }
                bool keepMax = ((tid & k) == 0) == ((tid & j) == 0);
                u64 mx = (x > y) ? x : y;
                u64 mn = (x > y) ? y : x;
                x = keepMax ? mx : mn;
            }
        }
    }

    // ---- on-demand box decode for own candidate ----
    float myV = __uint_as_float((u32)(x >> 32));
    float myY1 = 0.f, myX1 = 0.f, myY2 = 0.f, myX2 = 0.f, myAr = 0.f;
    u32 idx = ~(u32)x;
    if (tid < KCAND && idx < (u32)NANCH) {
        float4 d = ((const float4*)deltas)[(size_t)b * NANCH + idx];
        float4 a = ((const float4*)anchors)[idx];
        float ah = a.z - a.x, aw = a.w - a.y;
        float acy = a.x + 0.5f * ah, acx = a.y + 0.5f * aw;
        float cy = (d.x * 0.1f) * ah + acy;
        float cx = (d.y * 0.1f) * aw + acx;
        float hh2 = expf(d.z * 0.2f) * ah;
        float ww2 = expf(d.w * 0.2f) * aw;
        myY1 = cy - 0.5f * hh2; myX1 = cx - 0.5f * ww2;
        myY2 = cy + 0.5f * hh2; myX2 = cx + 0.5f * ww2;
        myAr = (myY2 - myY1) * (myX2 - myX1);
    } else {
        myV = 0.f;
    }
    __syncthreads();   // selection-phase LDS reads done before overlay write
    cbY1[tid] = myY1; cbX1[tid] = myX1; cbY2[tid] = myY2; cbX2[tid] = myX2;
    cbAr[tid] = myAr; cVal[tid] = myV;

    // ---- tiled IoU + serial NMS with early exit at 20 kept ----
    u64 k0 = 0, k1 = 0, k2 = 0, k3 = 0;
    int KPw = 0;
    for (int t0 = 0; t0 < 4; ++t0) {
        __syncthreads();                  // cb/iouT ready or free; sKP visible
        if (sKP >= PPC) break;            // uniform across block
        int rowBase = t0 * 64;
        int rows = KCAND - rowBase; if (rows > 64) rows = 64;
        for (int r = wv; r < rows; r += 4) {
            int i = rowBase + r;
            float y1i = cbY1[i], x1i = cbX1[i], y2i = cbY2[i], x2i = cbX2[i], ari = cbAr[i];
            for (int cg = 0; cg <= t0; ++cg) {
                int j = cg * 64 + lane;
                float ih = fminf(y2i, cbY2[j]) - fmaxf(y1i, cbY1[j]);
                ih = fmaxf(ih, 0.0f);
                float iw = fminf(x2i, cbX2[j]) - fmaxf(x1i, cbX1[j]);
                iw = fmaxf(iw, 0.0f);
                float inter = ih * iw;
                float iou = inter / (ari + cbAr[j] - inter + 1e-8f);
                u64 bal = __ballot(iou > 0.5f);
                if (lane == 0) iouT[r * 4 + cg] = bal;
            }
        }
        __syncthreads();                  // iouT ready
        if (tid < 64) {
            int i = rowBase + lane;
            u64 r0 = 0, r1 = 0, r2 = 0, r3 = 0;
            bool vld = false;
            if (lane < rows) {
                r0 = iouT[lane * 4 + 0]; r1 = iouT[lane * 4 + 1];
                r2 = iouT[lane * 4 + 2]; r3 = iouT[lane * 4 + 3];
                vld = cVal[i] > 0.5f;
            }
            for (int l = 0; l < rows; ++l) {
                int mydec = (vld && !((k0 & r0) | (k1 & r1) | (k2 & r2) | (k3 & r3))) ? 1 : 0;
                int d = __shfl(mydec, l, 64);
                if (d) {
                    u64 bit = 1ull << l;
                    if (t0 == 0) k0 |= bit; else if (t0 == 1) k1 |= bit;
                    else if (t0 == 2) k2 |= bit; else k3 |= bit;
                    ++KPw;
                    if (KPw >= PPC) break;   // uniform within wave (d broadcast)
                }
            }
            if (tid == 0) sKP = KPw;
        }
    }
    __syncthreads();

    if (tid < PPC) outS[tid] = 0.0f;
    if (tid < PPC * 4) outB[tid] = 0.0f;
    __syncthreads();

    // ---- emit first 20 kept (== top_k(kept_scores, 20) since values sorted) ----
    if (tid < 64) {
        int base = 0;
#pragma unroll
        for (int chunk = 0; chunk < 4; ++chunk) {
            u64 kw = (chunk == 0) ? k0 : (chunk == 1) ? k1 : (chunk == 2) ? k2 : k3;
            int i = chunk * 64 + tid;
            bool kept = ((kw >> tid) & 1ull) != 0;
            int rank = base + (int)__popcll(kw & ((1ull << tid) - 1ull));
            if (kept && rank < PPC && i < KCAND) {
                outS[rank] = cVal[i];
                outB[rank * 4 + 0] = cbY1[i];
                outB[rank * 4 + 1] = cbX1[i];
                outB[rank * 4 + 2] = cbY2[i];
                outB[rank * 4 + 3] = cbX2[i];
            }
            base += (int)__popcll(kw);
        }
    }
    __syncthreads();
    if (tid < PPC) clsScores[(size_t)bc * PPC + tid] = outS[tid];
    if (tid < PPC * 4) clsBoxes[(size_t)bc * PPC * 4 + tid] = outB[tid];
}

// -------------------- Kernel C: merge 21*20 per batch -> top 20 --------------------
__global__ __launch_bounds__(512) void kmerge(
    const float* __restrict__ clsScores, const float* __restrict__ clsBoxes,
    float* __restrict__ out)
{
#pragma clang fp contract(off)
    __shared__ u64 key[512];
    const int tid = threadIdx.x;
    const int b = blockIdx.x;
    const int F = NCLS * PPC;  // 420
    u64 kk = 0;
    if (tid < F) {
        float v = clsScores[(size_t)b * F + tid];
        kk = ((u64)__float_as_uint(v) << 32) | (u32)(~(u32)tid);
    }
    key[tid] = kk;
    for (int k = 2; k <= 512; k <<= 1)
        for (int j = k >> 1; j > 0; j >>= 1) {
            __syncthreads();
            int ixj = tid ^ j;
            if (ixj > tid) {
                u64 a = key[tid], bb = key[ixj];
                if (((tid & k) == 0) ? (a < bb) : (a > bb)) { key[tid] = bb; key[ixj] = a; }
            }
        }
    __syncthreads();
    if (tid < PTOT) {
        u64 kx = key[tid];
        float v = __uint_as_float((u32)(kx >> 32));
        u32 f = ~((u32)kx);
        bool valid = (v > 0.0f) && (f < (u32)F);
        float cls = valid ? (float)(f / PPC) : 0.0f;
        float* oB = out;
        float* oV = out + (size_t)BATCH * PTOT * 4;
        float* oL = oV + (size_t)BATCH * PTOT;
#pragma unroll
        for (int q = 0; q < 4; ++q) {
            float xq = 0.0f;
            if (valid) {
                xq = clsBoxes[((size_t)b * F + f) * 4 + q];
                xq = fminf(fmaxf(xq, 0.0f), 1.0f);
            }
            oB[((size_t)b * PTOT + tid) * 4 + q] = xq;
        }
        oV[(size_t)b * PTOT + tid] = v;
        oL[(size_t)b * PTOT + tid] = cls;
    }
}

extern "C" void kernel_launch(void* const* d_in, const int* in_sizes, int n_in,
                              void* d_out, int out_size, void* d_ws, size_t ws_size,
                              hipStream_t stream)
{
    const float* deltas  = (const float*)d_in[0];
    const float* labels  = (const float*)d_in[1];
    const float* anchors = (const float*)d_in[2];
    float* out = (float*)d_out;
    char* ws = (char*)d_ws;

    // ws layout (256B aligned)
    const size_t mskOff  = 0;          // B*N u8            =    558,848
    const size_t cntOff  = 558848;     // B*C u32           =      5,376
    const size_t csOff   = 564480;     // B*C*20 f32        =    107,520
    const size_t cbOff   = 672000;     // B*C*20*4 f32      =    430,080
    const size_t listOff = 1102336;    // B*C*CAP u64       = 22,020,096
    const size_t needT   = 23122432;

    unsigned char* msk = (unsigned char*)(ws + mskOff);
    u32* cnt         = (u32*)(ws + cntOff);
    float* clsScores = (float*)(ws + csOff);
    float* clsBoxes  = (float*)(ws + cbOff);
    u64* lists       = (u64*)(ws + listOff);
    int useT = (ws_size >= needT) ? 1 : 0;

    if (useT) hipMemsetAsync(cnt, 0, BATCH * NCLS * sizeof(u32), stream);
    dim3 gA((NANCH + 255) / 256, BATCH);
    kdecode<<<gA, 256, 0, stream>>>(labels, msk, lists, cnt, useT);
    knms<<<BATCH * NCLS, 256, 0, stream>>>(labels, msk, lists, cnt, deltas, anchors,
                                           clsScores, clsBoxes, useT);
    kmerge<<<BATCH, 512, 0, stream>>>(clsScores, clsBoxes, out);
}

// Round 10
// 58.429 us; speedup vs baseline: 1.6709x; 1.4473x over previous
//
#include <hip/hip_runtime.h>
#include <stdint.h>

typedef unsigned long long u64;
typedef unsigned int u32;
typedef unsigned short u16;

#define BATCH 64
#define NANCH 8732
#define NCHUNK 1092      // ceil(NANCH/8) u16-chunks (slow path)
#define NCLS 21
#define KCAND 200
#define CAP 2048         // per-(b,c) candidate list capacity
#define PPC 20
#define PTOT 20
#define PRETHR 0.9f
#define HWIN 1792        // fast-path hist window start: bin = (t16>>5)-HWIN in [0,256)

// ---------- Kernel A: argmax mask + prefiltered candidate append ----------
__global__ __launch_bounds__(256) void kdecode(
    const float* __restrict__ labels,
    unsigned char* __restrict__ msk, u64* __restrict__ lists,
    u32* __restrict__ cnt, int useT)
{
#pragma clang fp contract(off)
    const int n = blockIdx.x * 256 + threadIdx.x;
    const int b = blockIdx.y;
    const int lane = threadIdx.x & 63;
    const bool active = (n < NANCH);

    float v[NCLS];
#pragma unroll
    for (int c = 0; c < NCLS; ++c) v[c] = 0.0f;
    bool mk = false;
    if (active) {
        const float* lab = labels + ((size_t)b * NANCH + n) * NCLS;
#pragma unroll
        for (int c = 0; c < NCLS; ++c) v[c] = lab[c];
        float mx = v[0]; int am = 0;
#pragma unroll
        for (int c = 1; c < NCLS; ++c) if (v[c] > mx) { mx = v[c]; am = c; }
        mk = (am != 0);
        msk[(size_t)b * NANCH + n] = mk ? 1 : 0;
    }
    if (!useT) return;

    u32 myHits = 0;
#pragma unroll
    for (int c = 0; c < NCLS; ++c)
        if (active && mk && v[c] >= PRETHR) myHits |= (1u << c);

    u32 myCnt = 0;
#pragma unroll
    for (int c = 0; c < NCLS; ++c) {
        u64 m = __ballot((myHits >> c) & 1u);
        if (lane == c) myCnt = (u32)__popcll(m);
    }
    u32 myBase = 0;
    if (lane < NCLS) myBase = atomicAdd(&cnt[b * NCLS + lane], myCnt);

#pragma unroll
    for (int c = 0; c < NCLS; ++c) {
        u64 m = __ballot((myHits >> c) & 1u);
        u32 base = (u32)__shfl((int)myBase, c, 64);
        if ((m >> lane) & 1ull) {
            u32 rank = (u32)__popcll(m & ((1ull << lane) - 1ull));
            u32 slot = base + rank;
            if (slot < CAP)
                lists[((size_t)b * NCLS + c) * CAP + slot] =
                    ((u64)__float_as_uint(v[c]) << 32) | (u32)(~(u32)n);
        }
    }
}

__device__ __forceinline__ u64 shflxor64(u64 x, int m) {
    return (u64)__shfl_xor((long long)x, m, 64);
}

// Find bin where descending cumulative count crosses `need`; optionally total.
__device__ __forceinline__ void suffixFind(const u32* hist, u32* waveTot, int nb, int need,
                                           int* sSel, int* sAbove, int* sH, int* sTot,
                                           int tid, int lane, int wv)
{
    int K = (nb + 255) >> 8;
    int base = tid * K;
    u32 own = 0;
    for (int q = 0; q < K; ++q) { int bi = base + q; own += (bi < nb) ? hist[bi] : 0u; }
    u32 s = own;
#pragma unroll
    for (int d = 1; d < 64; d <<= 1) {
        u32 o = __shfl_down(s, d, 64);
        if (lane + d < 64) s += o;
    }
    if (lane == 0) waveTot[wv] = s;
    __syncthreads();
    if (tid == 0 && sTot) *sTot = (int)(waveTot[0] + waveTot[1] + waveTot[2] + waveTot[3]);
    u32 add = 0;
    for (int w = wv + 1; w < 4; ++w) add += waveTot[w];
    u32 cum = (s - own) + add;               // strictly above this thread's bins
    for (int q = K - 1; q >= 0; --q) {
        int bi = base + q;
        u32 hh = (bi < nb) ? hist[bi] : 0u;
        if (cum < (u32)need && cum + hh >= (u32)need) { *sSel = bi; *sAbove = (int)cum; *sH = (int)hh; }
        cum += hh;
    }
    __syncthreads();
}

// -------------------- Kernel B: per (b,c) top-200 + NMS + top-20 --------------------
__global__ __launch_bounds__(256) void knms(
    const float* __restrict__ labels, const unsigned char* __restrict__ msk,
    const u64* __restrict__ lists, const u32* __restrict__ cnt,
    const float* __restrict__ deltas, const float* __restrict__ anchors,
    float* __restrict__ clsScores, float* __restrict__ clsBoxes, int useT)
{
#pragma clang fp contract(off)
    // 8 KB overlay: selection = hist; post = cb*/cVal/iouT
    __shared__ __align__(16) char smem[8192];
    u32*   hist = (u32*)smem;
    float* cbY1 = (float*)smem;
    float* cbX1 = (float*)(smem + 1024);
    float* cbY2 = (float*)(smem + 2048);
    float* cbX2 = (float*)(smem + 3072);
    float* cbAr = (float*)(smem + 4096);
    float* cVal = (float*)(smem + 5120);
    u64*   iouT = (u64*)(smem + 6144);      // [64][4]
    __shared__ u64 candKey[256];
    __shared__ u32 waveTot[4];
    __shared__ float outS[PPC];
    __shared__ float outB[PPC * 4];
    __shared__ int sSel, sAbove, sH, sTot, sN, sKP;

    const int tid = threadIdx.x;
    const int lane = tid & 63;
    const int wv = tid >> 6;
    const int bc = blockIdx.x;
    const int b = bc / NCLS;
    const int c = bc % NCLS;

    const int nTHR = useT ? (int)cnt[bc] : -1;
    const bool fast = useT && (nTHR >= KCAND) && (nTHR <= CAP);

    if (fast) {
        // ---- fast path: candidates already prefiltered (all values >= 0.9) ----
        const u64* lst = lists + (size_t)bc * CAP;
        u64 kr[8];
#pragma unroll
        for (int q = 0; q < 8; ++q) {
            int i = q * 256 + tid;
            kr[q] = (i < nTHR) ? lst[i] : 0ull;
        }
        // windowed hist: bins [HWIN, HWIN+256) of t16>>5 (t16 >= 0xE666 guaranteed)
        hist[tid] = 0;
        if (tid == 0) { sSel = -1; sAbove = 0; sH = 0; sN = 0; sKP = 0; }
        __syncthreads();
#pragma unroll
        for (int q = 0; q < 8; ++q) {
            if (q * 256 + tid < nTHR) {
                float v = __uint_as_float((u32)(kr[q] >> 32));
                u32 t = (u32)(v * 65536.0f);
                atomicAdd(&hist[(t >> 5) - HWIN], 1u);
            }
        }
        __syncthreads();
        suffixFind(hist, waveTot, 256, KCAND, &sSel, &sAbove, &sH, nullptr, tid, lane, wv);
        int A = sAbove;
        u32 T16 = (u32)(HWIN + sSel) << 5;
        int cnt2 = A + sH;

        if (cnt2 > 256) {   // exact-t16 refinement (practically never)
            if (tid < 32) hist[tid] = 0;
            if (tid == 0) { sSel = -1; sAbove = 0; sH = 0; }
            __syncthreads();
#pragma unroll
            for (int q = 0; q < 8; ++q) {
                if (q * 256 + tid < nTHR) {
                    float v = __uint_as_float((u32)(kr[q] >> 32));
                    u32 t = (u32)(v * 65536.0f);
                    if (t >= T16 && t < T16 + 32) atomicAdd(&hist[t - T16], 1u);
                }
            }
            __syncthreads();
            suffixFind(hist, waveTot, 32, KCAND - A, &sSel, &sAbove, &sH, nullptr, tid, lane, wv);
            A += sAbove;
            T16 += (u32)sSel;
        }
        // compact t >= T16, wave-aggregated (order irrelevant: sorted below)
#pragma unroll
        for (int q = 0; q < 8; ++q) {
            int i = q * 256 + tid;
            bool pred = (i < nTHR);
            if (pred) {
                float v = __uint_as_float((u32)(kr[q] >> 32));
                pred = ((u32)(v * 65536.0f) >= T16);
            }
            u64 m = __ballot(pred);
            if (m) {
                int base = 0;
                if (lane == 0) base = atomicAdd(&sN, (int)__popcll(m));
                base = __shfl(base, 0, 64);
                if (pred) {
                    int slot = base + (int)__popcll(m & ((1ull << lane) - 1ull));
                    if (slot < 256) candKey[slot] = kr[q];
                }
            }
        }
    } else {
        // ---- slow fallback: full scan from labels+msk (rarely taken; R5-verbatim) ----
        uint4 rc[5];
        for (int q = 0; q < 5; ++q) {
            int chunk = q * 256 + tid;
            u32 w4[4] = {0, 0, 0, 0};
            if (chunk < NCHUNK) {
                for (int w = 0; w < 4; ++w)
                    for (int h = 0; h < 2; ++h) {
                        int n = chunk * 8 + w * 2 + h;
                        u32 t = 0;
                        if (n < NANCH && msk[(size_t)b * NANCH + n]) {
                            float v = labels[((size_t)b * NANCH + n) * NCLS + c];
                            t = (u32)(v * 65536.0f);
                        }
                        w4[w] |= t << (16 * h);
                    }
            }
            rc[q] = make_uint4(w4[0], w4[1], w4[2], w4[3]);
        }
        for (int q = tid; q < 1024; q += 256) hist[1024 + q] = 0;
        if (tid == 0) { sSel = -1; sAbove = 0; sH = 0; sTot = 0; sN = 0; sKP = 0; }
        __syncthreads();
#pragma unroll
        for (int q = 0; q < 5; ++q) {
            if (q * 256 + tid < NCHUNK) {
                u32 w4[4] = {rc[q].x, rc[q].y, rc[q].z, rc[q].w};
#pragma unroll
                for (int w = 0; w < 4; ++w) {
                    u32 lo = w4[w] & 0xFFFFu, hi = w4[w] >> 16;
                    if (lo & 0x8000u) atomicAdd(&hist[lo >> 5], 1u);
                    if (hi & 0x8000u) atomicAdd(&hist[hi >> 5], 1u);
                }
            }
        }
        __syncthreads();
        suffixFind(hist + 1024, waveTot, 1024, KCAND, &sSel, &sAbove, &sH, &sTot, tid, lane, wv);
        int A; int cnt2; u32 T16;
        if (sTot < KCAND) { T16 = 32768u; A = 0; cnt2 = sTot; }
        else { A = sAbove; T16 = (u32)(1024 + sSel) << 5; cnt2 = A + sH; }
        if (cnt2 > 256) {
            if (tid < 32) hist[tid] = 0;
            if (tid == 0) { sSel = -1; sAbove = 0; sH = 0; }
            __syncthreads();
#pragma unroll
            for (int q = 0; q < 5; ++q) {
                if (q * 256 + tid < NCHUNK) {
                    u32 w4[4] = {rc[q].x, rc[q].y, rc[q].z, rc[q].w};
#pragma unroll
                    for (int w = 0; w < 4; ++w) {
                        u32 lo = w4[w] & 0xFFFFu, hi = w4[w] >> 16;
                        if (lo >= T16 && lo < T16 + 32) atomicAdd(&hist[lo - T16], 1u);
                        if (hi >= T16 && hi < T16 + 32) atomicAdd(&hist[hi - T16], 1u);
                    }
                }
            }
            __syncthreads();
            suffixFind(hist, waveTot, 32, KCAND - A, &sSel, &sAbove, &sH, nullptr, tid, lane, wv);
            A += sAbove;
            T16 += (u32)sSel;
        }
#pragma unroll
        for (int q = 0; q < 5; ++q) {
            int chunk = q * 256 + tid;
            if (chunk < NCHUNK) {
                u32 w4[4] = {rc[q].x, rc[q].y, rc[q].z, rc[q].w};
#pragma unroll
                for (int w = 0; w < 4; ++w) {
#pragma unroll
                    for (int h = 0; h < 2; ++h) {
                        u32 t = (h == 0) ? (w4[w] & 0xFFFFu) : (w4[w] >> 16);
                        if (t >= T16) {
                            int n = chunk * 8 + w * 2 + h;
                            float v = labels[((size_t)b * NANCH + n) * NCLS + c];
                            int slot = atomicAdd(&sN, 1);
                            if (slot < 256)
                                candKey[slot] = ((u64)__float_as_uint(v) << 32) | (u32)(~(u32)n);
                        }
                    }
                }
            }
        }
    }
    __syncthreads();
    int nc = sN; if (nc > 256) nc = 256;

    // ---- register bitonic sort desc on 256 keys (shfl_xor j<64, LDS j>=64) ----
    u64 x = (tid < nc) ? candKey[tid] : 0ull;
    for (int k = 2; k <= 256; k <<= 1) {
        for (int j = k >> 1; j > 0; j >>= 1) {
            u64 y;
            if (j < 64) {
                y = shflxor64(x, j);
            } else {
                __syncthreads();
                candKey[tid] = x;
                __syncthreads();
                y = candKey[tid ^ j];
            }
            bool keepMax = ((tid & k) == 0) == ((tid & j) == 0);
            u64 mx = (x > y) ? x : y;
            u64 mn = (x > y) ? y : x;
            x = keepMax ? mx : mn;
        }
    }
    // x = tid-th largest (value desc, index asc) == exact top_k order

    // ---- on-demand box decode for own candidate ----
    float myV = __uint_as_float((u32)(x >> 32));
    float myY1 = 0.f, myX1 = 0.f, myY2 = 0.f, myX2 = 0.f, myAr = 0.f;
    u32 idx = ~(u32)x;
    if (tid < KCAND && idx < (u32)NANCH) {
        float4 d = ((const float4*)deltas)[(size_t)b * NANCH + idx];
        float4 a = ((const float4*)anchors)[idx];
        float ah = a.z - a.x, aw = a.w - a.y;
        float acy = a.x + 0.5f * ah, acx = a.y + 0.5f * aw;
        float cy = (d.x * 0.1f) * ah + acy;
        float cx = (d.y * 0.1f) * aw + acx;
        float hh2 = expf(d.z * 0.2f) * ah;
        float ww2 = expf(d.w * 0.2f) * aw;
        myY1 = cy - 0.5f * hh2; myX1 = cx - 0.5f * ww2;
        myY2 = cy + 0.5f * hh2; myX2 = cx + 0.5f * ww2;
        myAr = (myY2 - myY1) * (myX2 - myX1);
    } else {
        myV = 0.f;
    }
    __syncthreads();   // selection-phase LDS reads done before overlay write
    cbY1[tid] = myY1; cbX1[tid] = myX1; cbY2[tid] = myY2; cbX2[tid] = myX2;
    cbAr[tid] = myAr; cVal[tid] = myV;

    // ---- tiled IoU + serial NMS with early exit at 20 kept ----
    u64 k0 = 0, k1 = 0, k2 = 0, k3 = 0;
    int KPw = 0;
    for (int t0 = 0; t0 < 4; ++t0) {
        __syncthreads();                  // cb/iouT ready or free; sKP visible
        if (sKP >= PPC) break;            // uniform across block
        int rowBase = t0 * 64;
        int rows = KCAND - rowBase; if (rows > 64) rows = 64;
        for (int r = wv; r < rows; r += 4) {
            int i = rowBase + r;
            float y1i = cbY1[i], x1i = cbX1[i], y2i = cbY2[i], x2i = cbX2[i], ari = cbAr[i];
            for (int cg = 0; cg <= t0; ++cg) {
                int j = cg * 64 + lane;
                float ih = fminf(y2i, cbY2[j]) - fmaxf(y1i, cbY1[j]);
                ih = fmaxf(ih, 0.0f);
                float iw = fminf(x2i, cbX2[j]) - fmaxf(x1i, cbX1[j]);
                iw = fmaxf(iw, 0.0f);
                float inter = ih * iw;
                float iou = inter / (ari + cbAr[j] - inter + 1e-8f);
                u64 bal = __ballot(iou > 0.5f);
                if (lane == 0) iouT[r * 4 + cg] = bal;
            }
        }
        __syncthreads();                  // iouT ready
        if (tid < 64) {
            int i = rowBase + lane;
            u64 r0 = 0, r1 = 0, r2 = 0, r3 = 0;
            bool vld = false;
            if (lane < rows) {
                r0 = iouT[lane * 4 + 0]; r1 = iouT[lane * 4 + 1];
                r2 = iouT[lane * 4 + 2]; r3 = iouT[lane * 4 + 3];
                vld = cVal[i] > 0.5f;
            }
            for (int l = 0; l < rows; ++l) {
                int mydec = (vld && !((k0 & r0) | (k1 & r1) | (k2 & r2) | (k3 & r3))) ? 1 : 0;
                int d = __shfl(mydec, l, 64);
                if (d) {
                    u64 bit = 1ull << l;
                    if (t0 == 0) k0 |= bit; else if (t0 == 1) k1 |= bit;
                    else if (t0 == 2) k2 |= bit; else k3 |= bit;
                    ++KPw;
                    if (KPw >= PPC) break;   // uniform within wave (d broadcast)
                }
            }
            if (tid == 0) sKP = KPw;
        }
    }
    __syncthreads();

    if (tid < PPC) outS[tid] = 0.0f;
    if (tid < PPC * 4) outB[tid] = 0.0f;
    __syncthreads();

    // ---- emit first 20 kept (== top_k(kept_scores, 20) since values sorted) ----
    if (tid < 64) {
        int base = 0;
#pragma unroll
        for (int chunk = 0; chunk < 4; ++chunk) {
            u64 kw = (chunk == 0) ? k0 : (chunk == 1) ? k1 : (chunk == 2) ? k2 : k3;
            int i = chunk * 64 + tid;
            bool kept = ((kw >> tid) & 1ull) != 0;
            int rank = base + (int)__popcll(kw & ((1ull << tid) - 1ull));
            if (kept && rank < PPC && i < KCAND) {
                outS[rank] = cVal[i];
                outB[rank * 4 + 0] = cbY1[i];
                outB[rank * 4 + 1] = cbX1[i];
                outB[rank * 4 + 2] = cbY2[i];
                outB[rank * 4 + 3] = cbX2[i];
            }
            base += (int)__popcll(kw);
        }
    }
    __syncthreads();
    if (tid < PPC) clsScores[(size_t)bc * PPC + tid] = outS[tid];
    if (tid < PPC * 4) clsBoxes[(size_t)bc * PPC * 4 + tid] = outB[tid];
}

// -------------------- Kernel C: merge 21*20 per batch -> top 20 (hybrid sort) --------------------
__global__ __launch_bounds__(512) void kmerge(
    const float* __restrict__ clsScores, const float* __restrict__ clsBoxes,
    float* __restrict__ out)
{
#pragma clang fp contract(off)
    __shared__ u64 key[512];
    const int tid = threadIdx.x;
    const int b = blockIdx.x;
    const int F = NCLS * PPC;  // 420
    u64 x = 0;
    if (tid < F) {
        float v = clsScores[(size_t)b * F + tid];
        x = ((u64)__float_as_uint(v) << 32) | (u32)(~(u32)tid);
    }
    for (int k = 2; k <= 512; k <<= 1) {
        for (int j = k >> 1; j >= 1; j >>= 1) {
            u64 y;
            if (j < 64) {
                y = shflxor64(x, j);
            } else {
                __syncthreads();
                key[tid] = x;
                __syncthreads();
                y = key[tid ^ j];
            }
            bool keepMax = ((tid & k) == 0) == ((tid & j) == 0);
            u64 mx = x > y ? x : y;
            u64 mn = x > y ? y : x;
            x = keepMax ? mx : mn;
        }
    }
    if (tid < PTOT) {
        float v = __uint_as_float((u32)(x >> 32));
        u32 f = ~((u32)x);
        bool valid = (v > 0.0f) && (f < (u32)F);
        float cls = valid ? (float)(f / PPC) : 0.0f;
        float* oB = out;
        float* oV = out + (size_t)BATCH * PTOT * 4;
        float* oL = oV + (size_t)BATCH * PTOT;
#pragma unroll
        for (int q = 0; q < 4; ++q) {
            float xq = 0.0f;
            if (valid) {
                xq = clsBoxes[((size_t)b * F + f) * 4 + q];
                xq = fminf(fmaxf(xq, 0.0f), 1.0f);
            }
            oB[((size_t)b * PTOT + tid) * 4 + q] = xq;
        }
        oV[(size_t)b * PTOT + tid] = v;
        oL[(size_t)b * PTOT + tid] = cls;
    }
}

extern "C" void kernel_launch(void* const* d_in, const int* in_sizes, int n_in,
                              void* d_out, int out_size, void* d_ws, size_t ws_size,
                              hipStream_t stream)
{
    const float* deltas  = (const float*)d_in[0];
    const float* labels  = (const float*)d_in[1];
    const float* anchors = (const float*)d_in[2];
    float* out = (float*)d_out;
    char* ws = (char*)d_ws;

    // ws layout (256B aligned)
    const size_t mskOff  = 0;          // B*N u8            =    558,848
    const size_t cntOff  = 558848;     // B*C u32           =      5,376
    const size_t csOff   = 564480;     // B*C*20 f32        =    107,520
    const size_t cbOff   = 672000;     // B*C*20*4 f32      =    430,080
    const size_t listOff = 1102336;    // B*C*CAP u64       = 22,020,096
    const size_t needT   = 23122432;

    unsigned char* msk = (unsigned char*)(ws + mskOff);
    u32* cnt         = (u32*)(ws + cntOff);
    float* clsScores = (float*)(ws + csOff);
    float* clsBoxes  = (float*)(ws + cbOff);
    u64* lists       = (u64*)(ws + listOff);
    int useT = (ws_size >= needT) ? 1 : 0;

    if (useT) hipMemsetAsync(cnt, 0, BATCH * NCLS * sizeof(u32), stream);
    dim3 gA((NANCH + 255) / 256, BATCH);
    kdecode<<<gA, 256, 0, stream>>>(labels, msk, lists, cnt, useT);
    knms<<<BATCH * NCLS, 256, 0, stream>>>(labels, msk, lists, cnt, deltas, anchors,
                                           clsScores, clsBoxes, useT);
    kmerge<<<BATCH, 512, 0, stream>>>(clsScores, clsBoxes, out);
}